// Round 11
// baseline (102.410 us; speedup 1.0000x reference)
//
#include <hip/hip_runtime.h>
#include <math.h>
#include <float.h>

// Problem constants (match reference)
#define BATCH 4
#define KCLS 16
#define NSRC 4096
#define NTGT 16384

// geometry: 512 threads = 8 waves; 8 targets/lane -> 512 targets/block;
// sources split 8-ways across blocks (grid = 4*32*8 = 1024 -> 4 blocks/CU);
// each block stages its 512-source chunk in 8 KB LDS (reduce alias: 32 KB).
#define THREADS 512
#define WAVES 8
#define TPL 8                               // targets per lane
#define TGT_PER_BLOCK 512                   // 64 lanes * TPL
#define SPLITS 8
#define CHUNK (NSRC / SPLITS)               // 512 sources per block
#define STRIPE (CHUNK / WAVES)              // 64 iterations per wave

// Main kernel: per-(target, source-chunk) argmin partials, bit-exact np
// numerics (verified absmax=0.0 R5-R9):
//   ss/tt: squares rounded individually, then sequential sum
//   dot  : rn(tx*sx); fma(ty,sy,.); fma(tz,sz,.)
//   d2   : fma(-2, dot, rn(tt+ss))
// Partial = packed u64 (ordered_float(d2)<<32 | idx); u64-min over packed
// == lexicographic (d2, first index) == np.argmin tie-break.
// use_slots!=0: store partial to private slot wsP[target*SPLITS+split]
// use_slots==0: atomicMin into ws64[target] (requires 0xFF pre-init).
__global__ __launch_bounds__(THREADS) void nn_partial_kernel(
    const float* __restrict__ source_pos,   // [B, 3, NS]
    const float* __restrict__ target_pos,   // [B, 3, NT]
    unsigned long long* __restrict__ wsP,   // [B*NT*SPLITS] slot mode
    unsigned long long* __restrict__ ws64,  // [B*NT] atomic mode
    int use_slots)
{
    // 32 KB: [0,8K) source stage; aliased after the scan as
    // smin[8][512] (16 KB) | sidx[8][512] (16 KB) = 32 KB
    __shared__ float4 ls[TGT_PER_BLOCK * WAVES / 2];

    int tid = threadIdx.x;
    int lane = tid & 63;
    int wave = tid >> 6;                    // 0..7

    // grid decode: blocksPerBatch = 32 tgroups * 8 splits = 256
    int b = blockIdx.x >> 8;
    int rem = blockIdx.x & 255;
    int tg = rem >> 3;
    int split = rem & 7;
    int tbase = tg * TGT_PER_BLOCK;
    int cg = split * CHUNK;                 // this block's source-chunk base

    // stage chunk: 512 sources, 1 per thread (coalesced x/y/z streams)
    const float* sxp = source_pos + (size_t)b * 3 * NSRC;
    const float* syp = sxp + NSRC;
    const float* szp = sxp + 2 * NSRC;
    {
        int s = tid;                        // CHUNK == THREADS
        float x = sxp[cg + s], y = syp[cg + s], z = szp[cg + s];
        float ss = __fadd_rn(__fadd_rn(__fmul_rn(x, x), __fmul_rn(y, y)),
                             __fmul_rn(z, z));
        ls[s] = make_float4(x, y, z, ss);
    }

    // eight targets per lane: t_j = tbase + 64*j + lane (coalesced loads)
    const float* tp = target_pos + (size_t)b * 3 * NTGT;
    float tx[TPL], ty[TPL], tz[TPL], tt[TPL];
#pragma unroll
    for (int j = 0; j < TPL; ++j) {
        int t = tbase + 64 * j + lane;
        tx[j] = tp[t]; ty[j] = tp[NTGT + t]; tz[j] = tp[2 * NTGT + t];
        tt[j] = __fadd_rn(__fadd_rn(__fmul_rn(tx[j], tx[j]),
                                    __fmul_rn(ty[j], ty[j])),
                          __fmul_rn(tz[j], tz[j]));
    }

    __syncthreads();

    int lbase = wave * STRIPE;              // this wave's stripe in the chunk
    int gbase = cg + lbase;                 // global source index base (uniform)
    float best[TPL];
    int bi[TPL];
#pragma unroll
    for (int j = 0; j < TPL; ++j) { best[j] = FLT_MAX; bi[j] = 0; }

#pragma unroll 8
    for (int i = 0; i < STRIPE; ++i) {
        float4 f = ls[lbase + i];           // wave-uniform -> LDS broadcast
        int cand = gbase + i;
#pragma unroll
        for (int j = 0; j < TPL; ++j) {
            float acc = __fmul_rn(tx[j], f.x);
            acc = __fmaf_rn(ty[j], f.y, acc);
            acc = __fmaf_rn(tz[j], f.z, acc);
            float d2 = __fmaf_rn(-2.0f, acc, __fadd_rn(tt[j], f.w));
            if (d2 < best[j]) { best[j] = d2; bi[j] = cand; }  // strict '<'
        }
    }

    __syncthreads();                        // done READING ls before aliasing

    float* smin = (float*)ls;
    int* sidx = (int*)(smin + WAVES * TGT_PER_BLOCK);
#pragma unroll
    for (int j = 0; j < TPL; ++j) {
        smin[wave * TGT_PER_BLOCK + 64 * j + lane] = best[j];
        sidx[wave * TGT_PER_BLOCK + 64 * j + lane] = bi[j];
    }
    __syncthreads();

    {
        int t = tid;                        // TGT_PER_BLOCK == THREADS
        float m = smin[t];
        int mi = sidx[t];
#pragma unroll
        for (int j = 1; j < WAVES; ++j) {
            float mj = smin[j * TGT_PER_BLOCK + t];
            int ij = sidx[j * TGT_PER_BLOCK + t];
            // lexicographic (value, index): earliest global index wins on ties
            if (mj < m || (mj == m && ij < mi)) { m = mj; mi = ij; }
        }
        // total-order map: monotone wrt float '<' (handles negatives)
        unsigned u = __float_as_uint(m);
        unsigned ord = (u & 0x80000000u) ? ~u : (u | 0x80000000u);
        unsigned long long packed =
            ((unsigned long long)ord << 32) | (unsigned)mi;
        size_t gt = (size_t)b * NTGT + tbase + t;
        if (use_slots)
            wsP[gt * SPLITS + split] = packed;      // private slot, no init
        else
            atomicMin(&ws64[gt], packed);           // needs 0xFF pre-init
    }
}

// Combine: reduce partials (slot mode: u64-min over 8 slots; atomic mode:
// single read), then lazy gate gather + sigmoid.
__global__ __launch_bounds__(256) void gate_kernel(
    const unsigned long long* __restrict__ wsP,   // [B*NT*SPLITS]
    const unsigned long long* __restrict__ ws64,  // [B*NT]
    const float* __restrict__ sem_logits,         // [B, K, NS]
    float* __restrict__ out,                      // [B*NT]
    int use_slots)
{
    int gt = blockIdx.x * 256 + threadIdx.x;      // 0 .. B*NT-1
    int b = gt / NTGT;

    unsigned long long m;
    if (use_slots) {
        const unsigned long long* p = wsP + (size_t)gt * SPLITS;
        m = p[0];
#pragma unroll
        for (int k = 1; k < SPLITS; ++k) {
            unsigned long long v = p[k];
            if (v < m) m = v;               // u64 min == lexicographic (d2, idx)
        }
    } else {
        m = ws64[gt];
    }
    int mi = (int)(m & 0xFFFFFFFFull);

    const float* lg = sem_logits + (size_t)b * KCLS * NSRC + mi;
    float mm = lg[0];
#pragma unroll
    for (int k = 1; k < KCLS; ++k) mm = fmaxf(mm, lg[(size_t)k * NSRC]);
    out[gt] = 1.0f / (1.0f + expf(-mm));
}

extern "C" void kernel_launch(void* const* d_in, const int* in_sizes, int n_in,
                              void* d_out, int out_size, void* d_ws, size_t ws_size,
                              hipStream_t stream) {
    const float* sem_logits = (const float*)d_in[0];   // [B,K,NS] fp32
    const float* source_pos = (const float*)d_in[1];   // [B,3,NS] fp32
    const float* target_pos = (const float*)d_in[2];   // [B,3,NT] fp32
    float* out = (float*)d_out;                        // [B,NT,1] fp32

    const size_t slots_bytes =
        sizeof(unsigned long long) * (size_t)BATCH * NTGT * SPLITS;  // 4 MB
    int use_slots = (ws_size >= slots_bytes) ? 1 : 0;  // launch-time constant

    unsigned long long* wsP = (unsigned long long*)d_ws;
    unsigned long long* ws64 = (unsigned long long*)d_ws;

    if (!use_slots) {
        // atomic fallback: init packed partials to u64-max (0xFF bytes)
        hipMemsetAsync(ws64, 0xFF,
                       sizeof(unsigned long long) * (size_t)BATCH * NTGT, stream);
    }

    nn_partial_kernel<<<BATCH * (NTGT / TGT_PER_BLOCK) * SPLITS, THREADS, 0, stream>>>(
        source_pos, target_pos, wsP, ws64, use_slots);
    gate_kernel<<<(BATCH * NTGT) / 256, 256, 0, stream>>>(
        wsP, ws64, sem_logits, out, use_slots);
}